// Round 3
// baseline (493.826 us; speedup 1.0000x reference)
//
#include <hip/hip_runtime.h>
#include <math.h>

// Problem constants
#define B_      32
#define C_IN    64
#define H_      4096
#define F_      8
#define OUT_CH  9          // F+1
#define KW      5          // F/2+1
#define BH      (B_ * H_)  // 131072 independent (b,h) problems
#define LOC_N   (BH * F_)  // 1048576 floats of loc output
#define NSWEEP  6
#define MIN_VEC 0.001f
#define SIG_STRIDE 36      // floats per problem in scratch (exactly 9 float4)

// Tournament (round-robin) parallel-Jacobi ordering: 7 rounds x 4 disjoint
// pairs covers all 28 (p,q) pairs. Disjoint rotations commute; angles
// computed from pre-round A still zero each pivot exactly.
__device__ const int PAIRS[7][4][2] = {
  {{0,7},{1,6},{2,5},{3,4}},
  {{0,6},{5,7},{1,4},{2,3}},
  {{0,5},{4,6},{3,7},{1,2}},
  {{0,4},{3,5},{2,6},{1,7}},
  {{0,3},{2,4},{1,5},{6,7}},
  {{0,2},{1,3},{4,7},{5,6}},
  {{0,1},{2,7},{3,6},{4,5}},
};

#define SYM(i,j) (((i) < (j)) ? A[i][j] : A[j][i])

__device__ __forceinline__ float softplus_f(float v) {
    return fmaxf(v, 0.0f) + __logf(1.0f + __expf(-fabsf(v)));
}

// ======================= Kernel A: conv + softplus ==========================
// 8 lanes per problem (channel-split). 1M threads -> ~20 waves/CU. HBM-bound.
__global__ __launch_bounds__(256, 5)
void conv_stage(const float* __restrict__ x,
                const float* __restrict__ w_n,
                const float* __restrict__ b_n,
                const float* __restrict__ w_p,
                const float* __restrict__ b_p,
                float* __restrict__ loc_out,   // = d_out (loc region)
                float* __restrict__ sig)       // d_ws: 36 floats / problem
{
    const int lane = threadIdx.x & 63;
    const int wv   = threadIdx.x >> 6;             // wave in block, 0..3
    const int p    = lane & 7;                     // problem slot in wave
    const int cg   = lane >> 3;                    // channel group, 0..7
    const int t    = blockIdx.x * 32 + wv * 8 + p; // problem id, 0..131071
    const int b    = t >> 12;
    const int h    = t & 4095;

    // x[b, c, h, w]; this lane covers channels c = cg*8 .. cg*8+7
    const float* xp = x + (((size_t)b * C_IN + (size_t)cg * 8) * H_ + h) * F_;

    float la[F_];
    #pragma unroll
    for (int w = 0; w < F_; ++w) la[w] = 0.0f;
    float pa[OUT_CH][4];
    #pragma unroll
    for (int o = 0; o < OUT_CH; ++o)
        #pragma unroll
        for (int wo = 0; wo < 4; ++wo) pa[o][wo] = 0.0f;

    #pragma unroll
    for (int cc = 0; cc < 8; ++cc) {
        const float4 x0 = *(const float4*)(xp + (size_t)cc * (H_ * F_));
        const float4 x1 = *(const float4*)(xp + (size_t)cc * (H_ * F_) + 4);
        const float xa[F_] = {x0.x, x0.y, x0.z, x0.w, x1.x, x1.y, x1.z, x1.w};
        const int c = cg * 8 + cc;

        const float wn = w_n[c];
        #pragma unroll
        for (int w = 0; w < F_; ++w) la[w] = fmaf(xa[w], wn, la[w]);

        const float* wpp = w_p + c * KW;           // + o*(C_IN*KW) below; L1-resident
        #pragma unroll
        for (int o = 0; o < OUT_CH; ++o) {
            #pragma unroll
            for (int k = 0; k < KW; ++k) {
                const float wval = wpp[o * (C_IN * KW) + k];
                #pragma unroll
                for (int wo = 0; wo < 4; ++wo)
                    pa[o][wo] = fmaf(xa[wo + k], wval, pa[o][wo]);
            }
        }
    }

    // Butterfly reduction across the 8 channel groups (lane strides 8,16,32).
    #pragma unroll
    for (int m = 8; m <= 32; m <<= 1) {
        #pragma unroll
        for (int w = 0; w < F_; ++w) la[w] += __shfl_xor(la[w], m, 64);
        #pragma unroll
        for (int o = 0; o < OUT_CH; ++o)
            #pragma unroll
            for (int wo = 0; wo < 4; ++wo)
                pa[o][wo] += __shfl_xor(pa[o][wo], m, 64);
    }

    // cg==0 lanes (8 per wave, one per problem) finalize + store.
    if (cg == 0) {
        // loc = softplus(conv1x1 + b_n) -> out[t*8 .. t*8+7]
        const float bn = b_n[0];
        float lv[F_];
        #pragma unroll
        for (int w = 0; w < F_; ++w) lv[w] = softplus_f(la[w] + bn);
        float* lo = loc_out + (size_t)t * F_;
        *(float4*)(lo)     = make_float4(lv[0], lv[1], lv[2], lv[3]);
        *(float4*)(lo + 4) = make_float4(lv[4], lv[5], lv[6], lv[7]);

        // sigma[k] = softplus(pa[k/4][k%4] + b_p[k/4]), k = 0..35
        float* sp = sig + (size_t)t * SIG_STRIDE;
        #pragma unroll
        for (int o = 0; o < OUT_CH; ++o) {
            const float bp = b_p[o];
            float4 s = make_float4(softplus_f(pa[o][0] + bp),
                                   softplus_f(pa[o][1] + bp),
                                   softplus_f(pa[o][2] + bp),
                                   softplus_f(pa[o][3] + bp));
            *(float4*)(sp + o * 4) = s;
        }
    }
}

// ======================= Kernel B: Jacobi eigen + PD ========================
__global__ __launch_bounds__(256, 2)
void eig_stage(const float* __restrict__ sig, float* __restrict__ out)
{
    const int t = blockIdx.x * 256 + threadIdx.x;

    float sf[36];
    {
        const float* sp = sig + (size_t)t * SIG_STRIDE;
        #pragma unroll
        for (int j = 0; j < 9; ++j) {
            const float4 v = *(const float4*)(sp + j * 4);
            sf[j * 4 + 0] = v.x; sf[j * 4 + 1] = v.y;
            sf[j * 4 + 2] = v.z; sf[j * 4 + 3] = v.w;
        }
    }

    float A[F_][F_];   // only j>=i maintained
    {
        int k = 0;
        #pragma unroll
        for (int i = 0; i < F_; ++i)
            #pragma unroll
            for (int j = i; j < F_; ++j) { A[i][j] = sf[k]; ++k; }
    }

    float V[F_][F_];
    #pragma unroll
    for (int i = 0; i < F_; ++i)
        #pragma unroll
        for (int j = 0; j < F_; ++j)
            V[i][j] = (i == j) ? 1.0f : 0.0f;

    for (int sweep = 0; sweep < NSWEEP; ++sweep) {
        #pragma unroll
        for (int r = 0; r < 7; ++r) {
            float cs[4], sn[4], tv[4];
            #pragma unroll
            for (int j = 0; j < 4; ++j) {
                const int p = PAIRS[r][j][0], q = PAIRS[r][j][1];
                const float apq = A[p][q];
                const float app = A[p][p];
                const float aqq = A[q][q];
                float th = (aqq - app) / (2.0f * apq);
                float tt = 1.0f / (fabsf(th) + sqrtf(fmaf(th, th, 1.0f)));
                tt = (th < 0.0f) ? -tt : tt;
                tt = (apq == 0.0f) ? 0.0f : tt;
                const float cc = 1.0f / sqrtf(fmaf(tt, tt, 1.0f));
                cs[j] = cc; sn[j] = tt * cc; tv[j] = tt;
            }
            #pragma unroll
            for (int j = 0; j < 4; ++j) {
                const int p = PAIRS[r][j][0], q = PAIRS[r][j][1];
                const float cc = cs[j], ss = sn[j], tt = tv[j];
                const float apq = A[p][q];
                A[p][p] = fmaf(-tt, apq, A[p][p]);
                A[q][q] = fmaf( tt, apq, A[q][q]);
                A[p][q] = 0.0f;
                #pragma unroll
                for (int i = 0; i < F_; ++i) {
                    if (i == p || i == q) continue;
                    const float aip = SYM(i, p);
                    const float aiq = SYM(i, q);
                    SYM(i, p) = fmaf(-ss, aiq, cc * aip);
                    SYM(i, q) = fmaf( ss, aip, cc * aiq);
                }
            }
            #pragma unroll
            for (int j = 0; j < 4; ++j) {
                const int p = PAIRS[r][j][0], q = PAIRS[r][j][1];
                const float cc = cs[j], ss = sn[j];
                #pragma unroll
                for (int i = 0; i < F_; ++i) {
                    const float u = V[i][p], v = V[i][q];
                    V[i][p] = fmaf(-ss, v, cc * u);
                    V[i][q] = fmaf( ss, u, cc * v);
                }
            }
        }
    }

    float lam[F_];
    #pragma unroll
    for (int k = 0; k < F_; ++k) lam[k] = fmaxf(A[k][k], MIN_VEC);

    float W[F_][F_];
    #pragma unroll
    for (int i = 0; i < F_; ++i)
        #pragma unroll
        for (int k = 0; k < F_; ++k)
            W[i][k] = V[i][k] * lam[k];

    float PD[F_][F_];
    #pragma unroll
    for (int i = 0; i < F_; ++i) {
        #pragma unroll
        for (int j = i; j < F_; ++j) {
            float acc = 0.0f;
            #pragma unroll
            for (int k = 0; k < F_; ++k)
                acc = fmaf(W[i][k], V[j][k], acc);
            PD[i][j] = acc;
            PD[j][i] = acc;
        }
    }

    float* po = out + LOC_N + (size_t)t * (F_ * F_);
    #pragma unroll
    for (int i = 0; i < F_; ++i) {
        *(float4*)(po + i * F_)     = make_float4(PD[i][0], PD[i][1], PD[i][2], PD[i][3]);
        *(float4*)(po + i * F_ + 4) = make_float4(PD[i][4], PD[i][5], PD[i][6], PD[i][7]);
    }
}

// =================== Fallback: R1 fused single kernel =======================
__global__ __launch_bounds__(256, 2)
void mgauss_fused(const float* __restrict__ x,
                  const float* __restrict__ w_n,
                  const float* __restrict__ b_n,
                  const float* __restrict__ w_p,
                  const float* __restrict__ b_p,
                  float* __restrict__ out)
{
    const int t = blockIdx.x * 256 + threadIdx.x;
    const int b = t >> 12;
    const int h = t & 4095;
    const float* xp = x + ((size_t)b * C_IN * H_ + h) * F_;

    float la[F_];
    #pragma unroll
    for (int w = 0; w < F_; ++w) la[w] = 0.0f;
    float pa[OUT_CH][4];
    #pragma unroll
    for (int o = 0; o < OUT_CH; ++o)
        #pragma unroll
        for (int wo = 0; wo < 4; ++wo) pa[o][wo] = 0.0f;

    #pragma unroll 4
    for (int c = 0; c < C_IN; ++c) {
        const float4 x0 = *(const float4*)(xp + (size_t)c * (H_ * F_));
        const float4 x1 = *(const float4*)(xp + (size_t)c * (H_ * F_) + 4);
        const float xa[F_] = {x0.x, x0.y, x0.z, x0.w, x1.x, x1.y, x1.z, x1.w};
        const float wn = w_n[c];
        #pragma unroll
        for (int w = 0; w < F_; ++w) la[w] = fmaf(xa[w], wn, la[w]);
        #pragma unroll
        for (int o = 0; o < OUT_CH; ++o)
            #pragma unroll
            for (int k = 0; k < KW; ++k) {
                const float wval = w_p[(o * C_IN + c) * KW + k];
                #pragma unroll
                for (int wo = 0; wo < 4; ++wo)
                    pa[o][wo] = fmaf(xa[wo + k], wval, pa[o][wo]);
            }
    }

    {
        const float bn = b_n[0];
        float lv[F_];
        #pragma unroll
        for (int w = 0; w < F_; ++w) lv[w] = softplus_f(la[w] + bn);
        float* lo = out + (size_t)t * F_;
        *(float4*)(lo)     = make_float4(lv[0], lv[1], lv[2], lv[3]);
        *(float4*)(lo + 4) = make_float4(lv[4], lv[5], lv[6], lv[7]);
    }

    float A[F_][F_];
    {
        float sigv[36];
        #pragma unroll
        for (int o = 0; o < OUT_CH; ++o) {
            const float bp = b_p[o];
            #pragma unroll
            for (int wo = 0; wo < 4; ++wo)
                sigv[o * 4 + wo] = softplus_f(pa[o][wo] + bp);
        }
        int k = 0;
        #pragma unroll
        for (int i = 0; i < F_; ++i)
            #pragma unroll
            for (int j = i; j < F_; ++j) { A[i][j] = sigv[k]; ++k; }
    }

    float V[F_][F_];
    #pragma unroll
    for (int i = 0; i < F_; ++i)
        #pragma unroll
        for (int j = 0; j < F_; ++j)
            V[i][j] = (i == j) ? 1.0f : 0.0f;

    for (int sweep = 0; sweep < NSWEEP; ++sweep) {
        #pragma unroll
        for (int r = 0; r < 7; ++r) {
            float cs[4], sn[4], tv[4];
            #pragma unroll
            for (int j = 0; j < 4; ++j) {
                const int p = PAIRS[r][j][0], q = PAIRS[r][j][1];
                const float apq = A[p][q];
                float th = (A[q][q] - A[p][p]) / (2.0f * apq);
                float tt = 1.0f / (fabsf(th) + sqrtf(fmaf(th, th, 1.0f)));
                tt = (th < 0.0f) ? -tt : tt;
                tt = (apq == 0.0f) ? 0.0f : tt;
                const float cc = 1.0f / sqrtf(fmaf(tt, tt, 1.0f));
                cs[j] = cc; sn[j] = tt * cc; tv[j] = tt;
            }
            #pragma unroll
            for (int j = 0; j < 4; ++j) {
                const int p = PAIRS[r][j][0], q = PAIRS[r][j][1];
                const float cc = cs[j], ss = sn[j], tt = tv[j];
                const float apq = A[p][q];
                A[p][p] = fmaf(-tt, apq, A[p][p]);
                A[q][q] = fmaf( tt, apq, A[q][q]);
                A[p][q] = 0.0f;
                #pragma unroll
                for (int i = 0; i < F_; ++i) {
                    if (i == p || i == q) continue;
                    const float aip = SYM(i, p);
                    const float aiq = SYM(i, q);
                    SYM(i, p) = fmaf(-ss, aiq, cc * aip);
                    SYM(i, q) = fmaf( ss, aip, cc * aiq);
                }
            }
            #pragma unroll
            for (int j = 0; j < 4; ++j) {
                const int p = PAIRS[r][j][0], q = PAIRS[r][j][1];
                const float cc = cs[j], ss = sn[j];
                #pragma unroll
                for (int i = 0; i < F_; ++i) {
                    const float u = V[i][p], v = V[i][q];
                    V[i][p] = fmaf(-ss, v, cc * u);
                    V[i][q] = fmaf( ss, u, cc * v);
                }
            }
        }
    }

    float lam[F_];
    #pragma unroll
    for (int k = 0; k < F_; ++k) lam[k] = fmaxf(A[k][k], MIN_VEC);
    float W[F_][F_];
    #pragma unroll
    for (int i = 0; i < F_; ++i)
        #pragma unroll
        for (int k = 0; k < F_; ++k)
            W[i][k] = V[i][k] * lam[k];
    float PD[F_][F_];
    #pragma unroll
    for (int i = 0; i < F_; ++i) {
        #pragma unroll
        for (int j = i; j < F_; ++j) {
            float acc = 0.0f;
            #pragma unroll
            for (int k = 0; k < F_; ++k)
                acc = fmaf(W[i][k], V[j][k], acc);
            PD[i][j] = acc;
            PD[j][i] = acc;
        }
    }
    float* po = out + LOC_N + (size_t)t * (F_ * F_);
    #pragma unroll
    for (int i = 0; i < F_; ++i) {
        *(float4*)(po + i * F_)     = make_float4(PD[i][0], PD[i][1], PD[i][2], PD[i][3]);
        *(float4*)(po + i * F_ + 4) = make_float4(PD[i][4], PD[i][5], PD[i][6], PD[i][7]);
    }
}

extern "C" void kernel_launch(void* const* d_in, const int* in_sizes, int n_in,
                              void* d_out, int out_size, void* d_ws, size_t ws_size,
                              hipStream_t stream) {
    const float* x   = (const float*)d_in[0];
    const float* w_n = (const float*)d_in[1];
    const float* b_n = (const float*)d_in[2];
    const float* w_p = (const float*)d_in[3];
    const float* b_p = (const float*)d_in[4];
    float* out = (float*)d_out;

    const size_t need = (size_t)BH * SIG_STRIDE * sizeof(float);  // 18.9 MB
    if (ws_size >= need) {
        float* sig = (float*)d_ws;
        hipLaunchKernelGGL(conv_stage, dim3(BH / 32), dim3(256), 0, stream,
                           x, w_n, b_n, w_p, b_p, out, sig);
        hipLaunchKernelGGL(eig_stage, dim3(BH / 256), dim3(256), 0, stream,
                           sig, out);
    } else {
        hipLaunchKernelGGL(mgauss_fused, dim3(BH / 256), dim3(256), 0, stream,
                           x, w_n, b_n, w_p, b_p, out);
    }
}